// Round 2
// baseline (1279.756 us; speedup 1.0000x reference)
//
#include <hip/hip_runtime.h>
#include <math.h>

#define B 512
#define T 500
#define ENC 1024
#define DEC 1024

// ---------------------------------------------------------------------------
// Kernel 1: sub[b,e] = sum_d dec[b,d] * W[e,d]   (C = A * W^T, both K-major)
// 32x32 tile, BK=32, 256 threads, 2x2 microtile, grid (32,16) = 512 blocks
// (2 blocks/CU). Next global tile prefetched into registers across barrier.
// ---------------------------------------------------------------------------
#define QM 32
#define QN 32
#define QK 32

__global__ __launch_bounds__(256) void gemm_sub(
    const float* __restrict__ A,   // [512,1024] decoderFeature
    const float* __restrict__ Wm,  // [1024,1024] W (row e, col d)
    float* __restrict__ C)         // [512,1024] sub
{
    __shared__ float As[QK][QM + 2];  // [k][m], stride 34 (even -> float2 aligned)
    __shared__ float Bs[QK][QN + 2];  // [k][n]

    const int tid = threadIdx.x;
    const int bm0 = blockIdx.y * QM;
    const int bn0 = blockIdx.x * QN;

    const int lr = tid >> 3;          // 0..31 tile row
    const int lc = (tid & 7) << 2;    // 0..28 k col (float4)
    const float* pa = A  + (size_t)(bm0 + lr) * DEC + lc;
    const float* pb = Wm + (size_t)(bn0 + lr) * DEC + lc;

    const int tx = tid & 15;          // n/2
    const int ty = tid >> 4;          // m/2

    float a00 = 0.f, a01 = 0.f, a10 = 0.f, a11 = 0.f;

    float4 a4 = *(const float4*)pa;
    float4 b4 = *(const float4*)pb;

    for (int k0 = 0; k0 < DEC; k0 += QK) {
        As[lc + 0][lr] = a4.x; As[lc + 1][lr] = a4.y;
        As[lc + 2][lr] = a4.z; As[lc + 3][lr] = a4.w;
        Bs[lc + 0][lr] = b4.x; Bs[lc + 1][lr] = b4.y;
        Bs[lc + 2][lr] = b4.z; Bs[lc + 3][lr] = b4.w;
        __syncthreads();
        if (k0 + QK < DEC) {
            a4 = *(const float4*)(pa + k0 + QK);
            b4 = *(const float4*)(pb + k0 + QK);
        }
#pragma unroll
        for (int k = 0; k < QK; k++) {
            float2 av = *(const float2*)&As[k][ty << 1];
            float2 bv = *(const float2*)&Bs[k][tx << 1];
            a00 = fmaf(av.x, bv.x, a00);
            a01 = fmaf(av.x, bv.y, a01);
            a10 = fmaf(av.y, bv.x, a10);
            a11 = fmaf(av.y, bv.y, a11);
        }
        __syncthreads();
    }

    float* c0 = C + (size_t)(bm0 + (ty << 1)) * ENC + bn0 + (tx << 1);
    *(float2*)c0         = make_float2(a00, a01);
    *(float2*)(c0 + ENC) = make_float2(a10, a11);
}

// ---------------------------------------------------------------------------
// Kernel 2: fused attention, per-wave online softmax, 4 rows/iteration.
// One block (8 waves) per batch. Wave w owns contiguous t in
// [w*chunk, min(len,(w+1)*chunk)), chunk = ceil(len/8). Per iteration the
// wave processes 4 rows: 16 dwordx4 loads in flight, 4 independent
// shuffle-reduce chains, one branch-free online-softmax update.
// enc is read exactly once, valid rows only.
// ---------------------------------------------------------------------------
#define NW 8
#define BLK (NW * 64)
#define RB 4

__global__ __launch_bounds__(BLK, 4) void attn_fused(
    const float* __restrict__ sub,   // [B, ENC]
    const float* __restrict__ enc,   // [B, T, ENC]
    const int* __restrict__ lens,    // [B]
    float* __restrict__ out_attn,    // [B, T]
    float* __restrict__ out_sum)     // [B, ENC]
{
    __shared__ float lds_scores[T];
    __shared__ float lds_m[NW];
    __shared__ float lds_l[NW];
    __shared__ float lds_o[NW][ENC];

    const int b    = blockIdx.x;
    const int tid  = threadIdx.x;
    const int wave = tid >> 6;
    const int lane = tid & 63;
    const int len  = lens[b];

    const float* encb = enc + (size_t)b * T * ENC;
    const float* subb = sub + (size_t)b * ENC;

    float4 s4[4];
#pragma unroll
    for (int c = 0; c < 4; c++)
        s4[c] = *(const float4*)(subb + c * 256 + 4 * lane);

    float4 acc4[4];
#pragma unroll
    for (int c = 0; c < 4; c++) acc4[c] = make_float4(0.f, 0.f, 0.f, 0.f);
    float m = -INFINITY;
    float l = 0.f;

    const int chunk = (len + NW - 1) / NW;
    const int t0 = wave * chunk;
    const int t1 = min(len, t0 + chunk);

    for (int t = t0; t < t1; t += RB) {
        const int nv = t1 - t;            // >= 1, wave-uniform
        float4 er[RB][4];
#pragma unroll
        for (int r = 0; r < RB; r++) {
            const int tr = t + ((r < nv) ? r : 0);   // clamp to a valid row
            const float* p = encb + (size_t)tr * ENC + 4 * lane;
#pragma unroll
            for (int c = 0; c < 4; c++)
                er[r][c] = *(const float4*)(p + 256 * c);
        }

        float d[RB];
#pragma unroll
        for (int r = 0; r < RB; r++) {
            float dd = 0.f;
#pragma unroll
            for (int c = 0; c < 4; c++) {
                dd = fmaf(er[r][c].x, s4[c].x, dd);
                dd = fmaf(er[r][c].y, s4[c].y, dd);
                dd = fmaf(er[r][c].z, s4[c].z, dd);
                dd = fmaf(er[r][c].w, s4[c].w, dd);
            }
            d[r] = dd;
        }

        // 4 independent 64-lane xor-reductions (latency overlapped)
#pragma unroll
        for (int off = 32; off > 0; off >>= 1) {
#pragma unroll
            for (int r = 0; r < RB; r++) d[r] += __shfl_xor(d[r], off, 64);
        }

#pragma unroll
        for (int r = 0; r < RB; r++)
            if (r >= nv) d[r] = -INFINITY;

        if (lane == 0) {
#pragma unroll
            for (int r = 0; r < RB; r++)
                if (r < nv) lds_scores[t + r] = d[r];
        }

        // branch-free online softmax update (row 0 always valid -> mx finite)
        const float mx    = fmaxf(fmaxf(d[0], d[1]), fmaxf(d[2], d[3]));
        const float m_new = fmaxf(m, mx);
        const float alpha = __expf(m - m_new);     // first iter: exp(-inf)=0
        float p[RB];
#pragma unroll
        for (int r = 0; r < RB; r++) p[r] = __expf(d[r] - m_new);
        l = fmaf(l, alpha, (p[0] + p[1]) + (p[2] + p[3]));
#pragma unroll
        for (int c = 0; c < 4; c++) {
            float4 a = acc4[c];
            a.x = a.x * alpha; a.y = a.y * alpha; a.z = a.z * alpha; a.w = a.w * alpha;
#pragma unroll
            for (int r = 0; r < RB; r++) {
                a.x = fmaf(p[r], er[r][c].x, a.x);
                a.y = fmaf(p[r], er[r][c].y, a.y);
                a.z = fmaf(p[r], er[r][c].z, a.z);
                a.w = fmaf(p[r], er[r][c].w, a.w);
            }
            acc4[c] = a;
        }
        m = m_new;
    }

    if (lane == 0) { lds_m[wave] = m; lds_l[wave] = l; }
#pragma unroll
    for (int c = 0; c < 4; c++)
        *(float4*)&lds_o[wave][c * 256 + 4 * lane] = acc4[c];
    __syncthreads();

    // combine 8 per-wave states (every thread, redundantly)
    float mg = -INFINITY;
#pragma unroll
    for (int w = 0; w < NW; w++) mg = fmaxf(mg, lds_m[w]);
    float scale[NW];
    float lg = 0.f;
#pragma unroll
    for (int w = 0; w < NW; w++) {
        float mw = lds_m[w];
        float s  = (mw == -INFINITY) ? 0.f : __expf(mw - mg);
        scale[w] = s;
        lg = fmaf(lds_l[w], s, lg);
    }
    const float inv_l = 1.f / lg;   // len >= 1 guarantees lg > 0

    const int e0 = 2 * tid;
    float o0 = 0.f, o1 = 0.f;
#pragma unroll
    for (int w = 0; w < NW; w++) {
        o0 = fmaf(scale[w], lds_o[w][e0], o0);
        o1 = fmaf(scale[w], lds_o[w][e0 + 1], o1);
    }
    *(float2*)(out_sum + (size_t)b * ENC + e0) = make_float2(o0 * inv_l, o1 * inv_l);

    for (int tt = tid; tt < T; tt += BLK) {
        float v = 0.f;
        if (tt < len) v = __expf(lds_scores[tt] - mg) * inv_l;
        out_attn[(size_t)b * T + tt] = v;
    }
}

// ---------------------------------------------------------------------------
extern "C" void kernel_launch(void* const* d_in, const int* in_sizes, int n_in,
                              void* d_out, int out_size, void* d_ws, size_t ws_size,
                              hipStream_t stream) {
    const float* dec  = (const float*)d_in[0];   // [512,1024]
    const float* enc  = (const float*)d_in[1];   // [512,500,1024]
    const int*   lens = (const int*)d_in[2];     // [512]
    const float* Wm   = (const float*)d_in[3];   // [1024,1024]

    float* out      = (float*)d_out;
    float* out_attn = out;                        // 512*500
    float* out_sum  = out + (size_t)B * T;        // 512*1024
    float* sub      = (float*)d_ws;               // 512*1024 floats = 2 MB scratch

    gemm_sub<<<dim3(ENC / QN, 512 / QM), 256, 0, stream>>>(dec, Wm, sub);
    attn_fused<<<dim3(B), BLK, 0, stream>>>(sub, enc, lens, out_attn, out_sum);
}